// Round 6
// baseline (366.711 us; speedup 1.0000x reference)
//
#include <hip/hip_runtime.h>

constexpr int B = 32, C = 64, N = 8192, R = 32, R3 = R * R * R;
constexpr int QUART = R3 / 4;  // 8192 voxels -> 32 KB slab (accum, x2 buffers)
constexpr int T = 1024;        // block size
constexpr int PPT = N / T;     // points per thread = 8

// native clang vectors (HIP's float4 is a struct; nontemporal builtins need
// true vector types)
typedef float f32x4 __attribute__((ext_vector_type(4)));
typedef unsigned int u32x4 __attribute__((ext_vector_type(4)));

// ---- workspace layout (~1.5 MB) -------------------------------------------
constexpr size_t IDX_OFF = 0;                            // B*N u16 (512 KB)
constexpr size_t PF_OFF  = (size_t)B * N * 2;            // B*N f32 (1 MB)

// LDS-only barrier: guards LDS hazards without the vmcnt(0) drain that
// __syncthreads() forces -- global stores (ncout/idx/voxout, exclusive
// regions never read in-kernel) stay in flight across it.
__device__ __forceinline__ void lds_barrier() {
  asm volatile("s_waitcnt lgkmcnt(0)" ::: "memory");
  __builtin_amdgcn_s_barrier();
  __builtin_amdgcn_sched_barrier(0);
}

// ---------------------------------------------------------------------------
// K1: fused per-batch prep (one block per batch). Unchanged from round 5
// (bit-identical outputs: f64 mean tree, f32 max-norm, voxel math, LDS
// count grid in 128 KB, vectorized ncout/idx/pf emission).
// ---------------------------------------------------------------------------
__global__ __launch_bounds__(1024) void prep_kernel(
    const float* __restrict__ coords, float* __restrict__ ncout,
    unsigned short* __restrict__ idx, float* __restrict__ pf) {
  __shared__ __align__(16) unsigned char smem[R3 * 4];  // 128 KB
  double* sm = (double*)smem;              // [1024] during mean phase
  float* smf = (float*)smem;               // [1024] during max phase
  unsigned int* cnt = (unsigned int*)smem; // [R3] during count phase

  const int b = blockIdx.x;
  const int t = threadIdx.x;
  const float* cb = coords + (size_t)b * 3 * N;

  // ---- mean (f64, identical reduction order to prior rounds) ----
  double sx = 0.0, sy = 0.0, sz = 0.0;
  for (int n = t; n < N; n += T) {
    sx += (double)cb[n];
    sy += (double)cb[N + n];
    sz += (double)cb[2 * N + n];
  }
  float mean[3];
  double vals[3] = {sx, sy, sz};
  for (int d = 0; d < 3; ++d) {
    sm[t] = vals[d];
    __syncthreads();
    for (int s = 512; s > 0; s >>= 1) {
      if (t < s) sm[t] += sm[t + s];
      __syncthreads();
    }
    mean[d] = (float)(sm[0] / (double)N);
    __syncthreads();
  }

  // ---- max point norm (f32; fmax associative, order-free) ----
  float mx = 0.0f;
  for (int n = t; n < N; n += T) {
    float dx = __fsub_rn(cb[n], mean[0]);
    float dy = __fsub_rn(cb[N + n], mean[1]);
    float dz = __fsub_rn(cb[2 * N + n], mean[2]);
    float n2 = __fadd_rn(__fadd_rn(__fmul_rn(dx, dx), __fmul_rn(dy, dy)),
                         __fmul_rn(dz, dz));
    mx = fmaxf(mx, n2);
  }
  smf[t] = mx;
  __syncthreads();
  for (int s = 512; s > 0; s >>= 1) {
    if (t < s) smf[t] = fmaxf(smf[t], smf[t + s]);
    __syncthreads();
  }
  const float dn = __fmul_rn(__fsqrt_rn(smf[0]), 2.0f);  // EPS == 0
  __syncthreads();  // everyone has read smf[0]; slab may now be reused

  // issue this thread's coord vector loads early (independent of LDS work;
  // L2-hot after the stats passes). n0 = t*8: thread-contiguous points.
  const int n0 = t * PPT;
  const f32x4 xa = *(const f32x4*)(cb + n0);
  const f32x4 xc = *(const f32x4*)(cb + n0 + 4);
  const f32x4 ya = *(const f32x4*)(cb + N + n0);
  const f32x4 yc = *(const f32x4*)(cb + N + n0 + 4);
  const f32x4 za = *(const f32x4*)(cb + 2 * N + n0);
  const f32x4 zc = *(const f32x4*)(cb + 2 * N + n0 + 4);

  // ---- zero the LDS count grid ----
  {
    u32x4* cz = (u32x4*)cnt;
    const u32x4 z4 = {0u, 0u, 0u, 0u};
#pragma unroll
    for (int k = 0; k < R3 / 4; k += T) cz[k + t] = z4;
  }
  lds_barrier();

  // ---- voxelize: per-point math identical to prior rounds ----
  int iv[PPT];
  f32x4 o0[2], o1[2], o2[2];
#pragma unroll
  for (int h = 0; h < 2; ++h) {
    const f32x4 xs = h ? xc : xa;
    const f32x4 ys = h ? yc : ya;
    const f32x4 zs = h ? zc : za;
#pragma unroll
    for (int j = 0; j < 4; ++j) {
      float t0 = __fmul_rn(__fadd_rn(__fdiv_rn(__fsub_rn(xs[j], mean[0]), dn), 0.5f), 32.0f);
      float t1 = __fmul_rn(__fadd_rn(__fdiv_rn(__fsub_rn(ys[j], mean[1]), dn), 0.5f), 32.0f);
      float t2 = __fmul_rn(__fadd_rn(__fdiv_rn(__fsub_rn(zs[j], mean[2]), dn), 0.5f), 32.0f);
      t0 = fminf(fmaxf(t0, 0.0f), 31.0f);
      t1 = fminf(fmaxf(t1, 0.0f), 31.0f);
      t2 = fminf(fmaxf(t2, 0.0f), 31.0f);
      o0[h][j] = t0;
      o1[h][j] = t1;
      o2[h][j] = t2;
      const int vx = (int)rintf(t0);  // half-to-even == np.round
      const int vy = (int)rintf(t1);
      const int vz = (int)rintf(t2);
      iv[h * 4 + j] = (vx * R + vy) * R + vz;  // [0, 32768)
    }
  }

  // ncout: pure output -> nontemporal vector stores
  float* nc = ncout + (size_t)b * 3 * N;
  __builtin_nontemporal_store(o0[0], (f32x4*)(nc + n0));
  __builtin_nontemporal_store(o0[1], (f32x4*)(nc + n0 + 4));
  __builtin_nontemporal_store(o1[0], (f32x4*)(nc + N + n0));
  __builtin_nontemporal_store(o1[1], (f32x4*)(nc + N + n0 + 4));
  __builtin_nontemporal_store(o2[0], (f32x4*)(nc + 2 * N + n0));
  __builtin_nontemporal_store(o2[1], (f32x4*)(nc + 2 * N + n0 + 4));

  // idx: packed u16x8 = one 16 B store (re-read by accum -> cached store)
  {
    u32x4 iw = {(unsigned)iv[0] | ((unsigned)iv[1] << 16),
                (unsigned)iv[2] | ((unsigned)iv[3] << 16),
                (unsigned)iv[4] | ((unsigned)iv[5] << 16),
                (unsigned)iv[6] | ((unsigned)iv[7] << 16)};
    *(u32x4*)(idx + (size_t)b * N + n0) = iw;
  }

  // count atomics
#pragma unroll
  for (int k = 0; k < PPT; ++k) atomicAdd(&cnt[iv[k]], 1u);
  lds_barrier();  // atomics complete; global stores stay in flight

  // ---- per-point reciprocal count from LDS (cached stores) ----
  f32x4 q0, q1;
#pragma unroll
  for (int j = 0; j < 4; ++j) {
    q0[j] = __fdiv_rn(1.0f, (float)cnt[iv[j]]);
    q1[j] = __fdiv_rn(1.0f, (float)cnt[iv[4 + j]]);
  }
  *(f32x4*)(pf + (size_t)b * N + n0) = q0;
  *(f32x4*)(pf + (size_t)b * N + n0 + 4) = q1;
}

// ---------------------------------------------------------------------------
// K2: one block per (b,c). ROUND 6: software-pipelined double-buffered
// quarter-slabs. Rounds 4/5 proved accum isn't issue- or L2-bound; the
// remaining theory is write-pipe duty cycle -- co-resident blocks run in
// lockstep, so during zero/scatter/barrier phases NO block issues global
// stores and the write pipe idles (~1/3 duty = the observed ~3x over the
// 55 us traffic floor). Pipeline: dump slab `cur` (ds_read -> global store,
// left in flight) WHILE zeroing+scattering slab `nxt`. Two 32 KB slabs =
// 64 KB LDS keeps the proven 2-blocks/CU residency; (1024,8) keeps the
// 64-VGPR cap. Hazard safety: a slab's dump ds_reads are separated from
// its next zero by two lgkm barriers; global stores never reread.
// Outputs bit-identical (same per-voxel adds; LDS-atomic order was already
// nondeterministic).
// ---------------------------------------------------------------------------
__global__ __launch_bounds__(1024, 8) void accum_kernel(
    const float* __restrict__ feats, const unsigned short* __restrict__ idx,
    const float* __restrict__ pf, float* __restrict__ voxout) {
  __shared__ float lds[2][QUART];  // 2 x 32 KB
  const int blk = blockIdx.x;  // b*C + c
  const int c = blk & (C - 1);
  const int b = blk >> 6;
  const int t = threadIdx.x;
  const int n0 = t * PPT;

  const unsigned short* ib = idx + (size_t)b * N;
  const float* pb = pf + (size_t)b * N;
  const float* fb = feats + ((size_t)b * C + c) * N;

  // 5 vector loads: u16x8 idx, 2x f32x4 pf (cached), 2x f32x4 feat (nt --
  // single-use stream, keep L2 for idx/pf)
  const u32x4 ip = *(const u32x4*)(ib + n0);
  const f32x4 p0 = *(const f32x4*)(pb + n0);
  const f32x4 p1 = *(const f32x4*)(pb + n0 + 4);
  const f32x4 f0 = __builtin_nontemporal_load((const f32x4*)(fb + n0));
  const f32x4 f1 = __builtin_nontemporal_load((const f32x4*)(fb + n0) + 1);

  int iv[PPT];
  float fv[PPT];
#pragma unroll
  for (int j = 0; j < 4; ++j) {
    iv[2 * j] = (int)(ip[j] & 0xffffu);
    iv[2 * j + 1] = (int)(ip[j] >> 16);
  }
#pragma unroll
  for (int j = 0; j < 4; ++j) {
    fv[j] = f0[j] * p0[j];
    fv[4 + j] = f1[j] * p1[j];
  }

  f32x4* lp0 = (f32x4*)lds[0];
  f32x4* lp1 = (f32x4*)lds[1];
  const f32x4 z = {0.f, 0.f, 0.f, 0.f};
  float* outb = voxout + ((size_t)b * C + c) * R3;

  // per thread per slab: QUART/4/T = 2 f32x4 slots (t and t+T)
#define ZERO_SLAB(LP)            \
  do {                           \
    (LP)[t] = z;                 \
    (LP)[t + T] = z;             \
  } while (0)

#define SCATTER(BUF, LO)                                          \
  do {                                                            \
    _Pragma("unroll") for (int k = 0; k < PPT; ++k) {             \
      const int loc = iv[k] - (LO);                               \
      if ((unsigned)loc < (unsigned)QUART)                        \
        atomicAdd(&(BUF)[loc], fv[k]);                            \
    }                                                             \
  } while (0)

#define DUMP(LP, Q)                                               \
  do {                                                            \
    f32x4* ob4 = (f32x4*)(outb + (Q) * QUART);                    \
    __builtin_nontemporal_store((LP)[t], ob4 + t);                \
    __builtin_nontemporal_store((LP)[t + T], ob4 + t + T);        \
  } while (0)

  // prologue: fill slab0 with quarter 0
  ZERO_SLAB(lp0);
  lds_barrier();
  SCATTER(lds[0], 0 * QUART);
  lds_barrier();

  // q=0: dump slab0 || prepare quarter 1 in slab1
  DUMP(lp0, 0);
  ZERO_SLAB(lp1);
  lds_barrier();
  SCATTER(lds[1], 1 * QUART);
  lds_barrier();

  // q=1: dump slab1 || prepare quarter 2 in slab0
  // (slab0's dump ds_reads are 2 barriers old -> safe to overwrite)
  DUMP(lp1, 1);
  ZERO_SLAB(lp0);
  lds_barrier();
  SCATTER(lds[0], 2 * QUART);
  lds_barrier();

  // q=2: dump slab0 || prepare quarter 3 in slab1
  DUMP(lp0, 2);
  ZERO_SLAB(lp1);
  lds_barrier();
  SCATTER(lds[1], 3 * QUART);
  lds_barrier();

  // q=3: final dump (kernel-end implicit drain)
  DUMP(lp1, 3);

#undef ZERO_SLAB
#undef SCATTER
#undef DUMP
}

extern "C" void kernel_launch(void* const* d_in, const int* in_sizes, int n_in,
                              void* d_out, int out_size, void* d_ws,
                              size_t ws_size, hipStream_t stream) {
  const float* feats  = (const float*)d_in[0];  // [B, C, N]
  const float* coords = (const float*)d_in[1];  // [B, 3, N]

  float* voxout = (float*)d_out;                // [B, C, R,R,R]
  float* ncout  = voxout + (size_t)B * C * R3;  // [B, 3, N]

  char* ws = (char*)d_ws;
  unsigned short* idx = (unsigned short*)(ws + IDX_OFF);
  float* pf           = (float*)(ws + PF_OFF);

  prep_kernel<<<B, 1024, 0, stream>>>(coords, ncout, idx, pf);
  accum_kernel<<<B * C, 1024, 0, stream>>>(feats, idx, pf, voxout);
}